// Round 1
// baseline (72.017 us; speedup 1.0000x reference)
//
#include <hip/hip_runtime.h>

// JointBilateral PAC upsample, S=4, K=5, PAD=1, OP=1.
// Shapes fixed by setup_inputs(): x (4,1,128,128), guide (4,3,512,512),
// weight (1,1,5,5) -> out (4,1,512,512).
//
// Derivation (see analysis): per output pixel (h,w), valid taps i satisfy
// (h+i-3)%4==0, 0<=h+i-3<509. Tap i0=(3-h)&3 is always valid; i=4 additionally
// valid iff i0==0 && h<508. Same along w. Valid taps always have the guidance
// neighbor (h+i-2, w+j-2) in range, so no boundary handling needed there.

#define HW_ (512 * 512)
#define XLW 128

__global__ __launch_bounds__(256) void jbu_kernel(
    const float* __restrict__ x,       // (4,1,128,128)
    const float* __restrict__ guide,   // (4,3,512,512)
    const float* __restrict__ weight,  // (25,)
    float* __restrict__ out)           // (4,1,512,512)
{
    int idx = blockIdx.x * blockDim.x + threadIdx.x;  // 4*512*512 threads exactly
    int w = idx & 511;
    int h = (idx >> 9) & 511;
    int b = idx >> 18;

    const float* gb = guide + (size_t)b * 3 * HW_;
    int cidx = h * 512 + w;
    float g0 = gb[cidx];
    float g1 = gb[HW_ + cidx];
    float g2 = gb[2 * HW_ + cidx];

    int i0 = (3 - (h & 3)) & 3;
    int ni = 1 + (int)(i0 == 0 && h < 508);
    int j0 = (3 - (w & 3)) & 3;
    int nj = 1 + (int)(j0 == 0 && w < 508);

    const float* xb = x + b * (XLW * XLW);

    float acc = 0.0f, norm = 0.0f;
    #pragma unroll
    for (int ti = 0; ti < 2; ++ti) {
        if (ti >= ni) break;
        int i  = i0 + 4 * ti;
        int a  = (h + i - 3) >> 2;     // low-res row
        int hn = h + i - 2;            // guidance neighbor row
        float di = (float)(i - 2);
        float di2 = 0.01f * di * di;
        #pragma unroll
        for (int tj = 0; tj < 2; ++tj) {
            if (tj >= nj) break;
            int j  = j0 + 4 * tj;
            int c  = (w + j - 3) >> 2; // low-res col
            int wn = w + j - 2;        // guidance neighbor col
            float dj = (float)(j - 2);
            int nidx = hn * 512 + wn;
            float d0 = gb[nidx]           - g0;
            float d1 = gb[HW_ + nidx]     - g1;
            float d2c = gb[2 * HW_ + nidx] - g2;
            float dist = 0.25f * (d0 * d0 + d1 * d1 + d2c * d2c)
                       + di2 + 0.01f * dj * dj;
            float kv = __expf(-0.5f * dist);
            norm += kv;
            acc  += kv * xb[a * XLW + c] * weight[(4 - i) * 5 + (4 - j)];
        }
    }
    out[idx] = acc / norm;
}

extern "C" void kernel_launch(void* const* d_in, const int* in_sizes, int n_in,
                              void* d_out, int out_size, void* d_ws, size_t ws_size,
                              hipStream_t stream) {
    const float* x      = (const float*)d_in[0];
    const float* guide  = (const float*)d_in[1];
    const float* weight = (const float*)d_in[2];
    float* out = (float*)d_out;

    int total = 4 * 512 * 512;   // == out_size
    (void)in_sizes; (void)n_in; (void)out_size; (void)d_ws; (void)ws_size;
    jbu_kernel<<<total / 256, 256, 0, stream>>>(x, guide, weight, out);
}

// Round 2
// 69.433 us; speedup vs baseline: 1.0372x; 1.0372x over previous
//
#include <hip/hip_runtime.h>

// JointBilateral PAC upsample, S=4, K=5, PAD=1, OP=1.
// x (4,1,128,128), guide (4,3,512,512), weight (1,1,5,5) -> out (4,1,512,512).
//
// Collapsed form: for output (h,w) with q=h>>2, m=w>>2:
//   row taps: a=q always (i=i0=(3-h)&3, di=i0-2); a=q+1 iff h%4==3 && q<127 (i=4, di=2)
//   col taps: c=m always;                          c=m+1 iff w%4==3 && m<127 (j=4, dj=2)
//   guidance neighbor for tap (a,c) is the sample site (4a+1, 4c+1) -- always in range.
//   kern = exp(-0.125*||g_site - g_center||^2 - 0.005*(di^2+dj^2)) * weight[(4-i)*5+(4-j)]
//   out  = sum(kern*x[a][c]) / sum(kern)
// One thread computes 4 consecutive w (shared site/x loads), float4 center load/store.

#define HW_ (512 * 512)

__global__ __launch_bounds__(256) void jbu_kernel(
    const float* __restrict__ x,       // (4,1,128,128)
    const float* __restrict__ guide,   // (4,3,512,512)
    const float* __restrict__ weight,  // (25,)
    float* __restrict__ out)           // (4,1,512,512)
{
    int tid = blockIdx.x * blockDim.x + threadIdx.x;  // 4*512*128 threads exactly
    int m = tid & 127;          // low-res col group
    int h = (tid >> 7) & 511;   // output row (wave-uniform)
    int b = tid >> 16;
    int q = h >> 2, rh = h & 3;

    const float* gb = guide + (size_t)b * 3 * HW_;
    const float* xb = x + b * 128 * 128;

    int cbase = h * 512 + 4 * m;
    float4 c0 = *(const float4*)(gb + cbase);
    float4 c1 = *(const float4*)(gb + HW_ + cbase);
    float4 c2 = *(const float4*)(gb + 2 * HW_ + cbase);
    float cc0[4] = {c0.x, c0.y, c0.z, c0.w};
    float cc1[4] = {c1.x, c1.y, c1.z, c1.w};
    float cc2[4] = {c2.x, c2.y, c2.z, c2.w};

    bool cs = (m < 127);              // col-secondary tap exists for sub-pixel p==3
    int  co = cs ? 4 : 0;             // clamped site offset
    int  xo = cs ? 1 : 0;
    float csf = cs ? 1.0f : 0.0f;

    // primary-row sample site (4q+1, 4m+1)
    int sr = (4 * q + 1) * 512 + 4 * m + 1;
    float s00_0 = gb[sr],      s00_1 = gb[HW_ + sr],      s00_2 = gb[2 * HW_ + sr];
    float s01_0 = gb[sr + co], s01_1 = gb[HW_ + sr + co], s01_2 = gb[2 * HW_ + sr + co];
    float x00 = xb[q * 128 + m];
    float x01 = xb[q * 128 + m + xo];

    int dip = ((3 - rh) & 3) - 2;
    float spr0 = 0.005f * (float)(dip * dip);     // primary-row spatial term
    const float spcl[4] = {0.005f, 0.0f, 0.005f, 0.02f};  // per-sub-pixel col term (folded)

    int i0wi = rh + 1;                // (4 - i0) = 4 - ((3-rh)&3) = rh+1 for rh in 0..3
    float wr0[5], wr1[5];
    #pragma unroll
    for (int k = 0; k < 5; ++k) { wr0[k] = weight[i0wi * 5 + k]; wr1[k] = weight[k]; }

    float acc[4] = {0, 0, 0, 0}, nrm[4] = {0, 0, 0, 0};

    // row tap 0 (always valid): col primary for all 4 sub-pixels
    #pragma unroll
    for (int p = 0; p < 4; ++p) {
        float d0 = s00_0 - cc0[p], d1 = s00_1 - cc1[p], d2 = s00_2 - cc2[p];
        float kv = __expf(-0.125f * (d0*d0 + d1*d1 + d2*d2) - spr0 - spcl[p]) * wr0[p + 1];
        nrm[p] += kv; acc[p] += kv * x00;
    }
    {   // col secondary (sub-pixel 3 only)
        float d0 = s01_0 - cc0[3], d1 = s01_1 - cc1[3], d2 = s01_2 - cc2[3];
        float kv = __expf(-0.125f * (d0*d0 + d1*d1 + d2*d2) - spr0 - 0.02f) * wr0[0] * csf;
        nrm[3] += kv; acc[3] += kv * x01;
    }

    if (rh == 3 && q < 127) {         // wave-uniform branch: secondary row tap
        int sr1 = sr + 4 * 512;
        float s10_0 = gb[sr1],      s10_1 = gb[HW_ + sr1],      s10_2 = gb[2 * HW_ + sr1];
        float s11_0 = gb[sr1 + co], s11_1 = gb[HW_ + sr1 + co], s11_2 = gb[2 * HW_ + sr1 + co];
        float x10 = xb[(q + 1) * 128 + m];
        float x11 = xb[(q + 1) * 128 + m + xo];
        #pragma unroll
        for (int p = 0; p < 4; ++p) {
            float d0 = s10_0 - cc0[p], d1 = s10_1 - cc1[p], d2 = s10_2 - cc2[p];
            float kv = __expf(-0.125f * (d0*d0 + d1*d1 + d2*d2) - 0.02f - spcl[p]) * wr1[p + 1];
            nrm[p] += kv; acc[p] += kv * x10;
        }
        float d0 = s11_0 - cc0[3], d1 = s11_1 - cc1[3], d2 = s11_2 - cc2[3];
        float kv = __expf(-0.125f * (d0*d0 + d1*d1 + d2*d2) - 0.04f) * wr1[0] * csf;
        nrm[3] += kv; acc[3] += kv * x11;
    }

    float4 o;
    o.x = acc[0] / nrm[0];
    o.y = acc[1] / nrm[1];
    o.z = acc[2] / nrm[2];
    o.w = acc[3] / nrm[3];
    *(float4*)(out + (size_t)b * HW_ + cbase) = o;
}

extern "C" void kernel_launch(void* const* d_in, const int* in_sizes, int n_in,
                              void* d_out, int out_size, void* d_ws, size_t ws_size,
                              hipStream_t stream) {
    const float* x      = (const float*)d_in[0];
    const float* guide  = (const float*)d_in[1];
    const float* weight = (const float*)d_in[2];
    float* out = (float*)d_out;

    (void)in_sizes; (void)n_in; (void)out_size; (void)d_ws; (void)ws_size;
    int total = 4 * 512 * 128;   // one thread per 4 output pixels
    jbu_kernel<<<total / 256, 256, 0, stream>>>(x, guide, weight, out);
}